// Round 10
// baseline (48.104 us; speedup 1.0000x reference)
//
#include <hip/hip_runtime.h>

// Problem constants (match reference setup_inputs)
#define K_SIZE 5
#define PAD 2
#define SAMPLE_NUM 15
#define DEPTH_MAX 192.0f

constexpr int B = 2, C = 32, H = 240, W = 320;
constexpr int HW  = H * W;
constexpr int BHW = B * HW;            // 153600
constexpr int TOT = B * C * HW;        // 4915200 feature dwords
constexpr int PPB = 64;                // pixels per block (quarter row, row-uniform)
constexpr int NBLK = BHW / PPB;        // 2400
constexpr int XCHUNK = NBLK / 8;       // 300 contiguous blocks per XCD

constexpr int WROWS = 5;               // staged rows (y-2 .. y+2, row-clamped)
constexpr int WCOLS = 68;              // staged cols (x0-2 .. x0+65)
constexpr int SEGS  = WCOLS / 4;       // 17 float4 segments per row
constexpr int CH_STRIDE = WROWS * WCOLS;          // 340 dwords per channel plane
constexpr int STAGE_TASKS = C * WROWS * SEGS;     // 2720 float4 tasks

typedef float float4a __attribute__((ext_vector_type(4), aligned(16)));
typedef float float4u __attribute__((ext_vector_type(4), aligned(4)));  // 4B-aligned ok

__global__ __launch_bounds__(256) void adaptive_sample_fused(
    const float* __restrict__ depth,      // [B,1,H,W]
    const float* __restrict__ sn,         // [B,3,H,W]
    const float* __restrict__ features,   // [B,C,H,W]
    const float* __restrict__ guide,      // [B,H,W,25]
    const int*   __restrict__ sample_idx, // [15]
    float* __restrict__ out,              // [B,C,H,W]
    float* __restrict__ feat_out)         // [B,C,H,W]
{
    __shared__ __align__(16) float lds_f[C * CH_STRIDE];      // 43,520 B
    __shared__ __align__(16) float w_lds[SAMPLE_NUM][WCOLS];  //  4,080 B

    // XCD-chunked swizzle: each XCD owns 300 contiguous blocks
    const int bid = blockIdx.x;
    const int blk = (bid & 7) * XCHUNK + (bid >> 3);

    const int t    = threadIdx.x;
    const int base = blk * PPB;           // first global pixel
    const int b    = base / HW;
    const int pix0 = base - b * HW;
    const int y    = pix0 / W;            // whole block is one row segment
    const int x0   = pix0 - y * W;        // in {0,64,128,192,256}
    const int planeBase = b * C * HW;     // flat base of this batch's feature planes

    // ---------------- stage feature window into LDS ----------------
    // lds_f[ch][r][xi] = features[b, ch, clamp(y-2+r), x0-2+xi]  (x unclamped:
    // overreach spills into adjacent rows/planes = junk at weight-0 positions;
    // only global buffer extremes need the exact per-element path)
    for (int i = t; i < STAGE_TASKS; i += 256) {
        int ch  = i / (WROWS * SEGS);
        int rem = i - ch * (WROWS * SEGS);
        int r   = rem / SEGS;
        int k   = rem - r * SEGS;
        int yy  = min(max(y - 2 + r, 0), H - 1);
        int flat = planeBase + ch * HW + yy * W + (x0 - 2 + k * 4);
        float4a v;
        if (flat >= 0 && flat <= TOT - 4) {
            float4u g = *(const float4u*)(features + flat);
            v = float4a{g.x, g.y, g.z, g.w};
        } else {
            // per-element clamp: exact for in-bounds positions, junk (w=0) for OOB
            #pragma unroll
            for (int j = 0; j < 4; ++j)
                v[j] = features[min(max(flat + j, 0), TOT - 1)];
        }
        *(float4a*)&lds_f[ch * CH_STRIDE + r * WCOLS + k * 4] = v;
    }

    // ---------------- weights + 16-lane softmax -> w_lds ----------------
    {
        const int s  = t & 15;            // sample slot (15 = pad lane)
        const int lq = t >> 4;            // 0..15
        const float* snb = sn + (size_t)b * 3 * HW;
        const float* db  = depth + (size_t)b * HW;

        const int pp = sample_idx[(s < SAMPLE_NUM) ? s : 0];
        const int dy = pp / K_SIZE - PAD;
        const int dx = pp - (pp / K_SIZE) * K_SIZE - PAD;

        #pragma unroll
        for (int kk = 0; kk < 4; ++kk) {
            const int lp  = kk * 16 + lq;   // local pixel 0..63 (same row y)
            const int x   = x0 + lp;
            const int pix = pix0 + lp;

            const int yy = y + dy, xx = x + dx;
            const bool inb = (s < SAMPLE_NUM) &&
                             (yy >= 0) && (yy < H) && (xx >= 0) && (xx < W);
            const int noff = min(max(yy, 0), H - 1) * W + min(max(xx, 0), W - 1);

            // unconditional loads; validity folded via selects
            const float d   = db[noff];
            const int   o   = pix * 3;  // center_n = RAW RESHAPE [B,3,H,W]->(B,H,W,3)
            const float cn0 = snb[o], cn1 = snb[o + 1], cn2 = snb[o + 2];
            const float d0  = snb[noff]          - cn0;
            const float d1  = snb[HW + noff]     - cn1;
            const float d2  = snb[2 * HW + noff] - cn2;
            const float gv  = guide[((size_t)b * HW + pix) * 25 + pp];

            const float diff = sqrtf(d0 * d0 + d1 * d1 + d2 * d2);
            const bool  ok   = inb && (d > 0.0f) && (d < DEPTH_MAX);
            const float prew = ok ? __expf(-0.5f * diff) * gv : 0.0f;

            // softmax across the 16-lane group (pad lane prew=0 can't raise max;
            // its exp term is excluded from the sum)
            float m = prew;
            #pragma unroll
            for (int mask = 1; mask < 16; mask <<= 1)
                m = fmaxf(m, __shfl_xor(m, mask, 16));
            float e = (s < SAMPLE_NUM) ? __expf(prew - m) : 0.0f;
            float sum = e;
            #pragma unroll
            for (int mask = 1; mask < 16; mask <<= 1)
                sum += __shfl_xor(sum, mask, 16);

            if (s < SAMPLE_NUM)
                w_lds[s][lp] = inb ? (e / sum) : 0.0f;  // OOB -> 0 (zero-pad feature)
        }
    }
    __syncthreads();

    // ---------------- gather: thread = (quad, channel-pair) ----------------
    {
        const int q  = t & 15;            // quad 0..15 (pixels x0+4q .. +3)
        const int cs = t >> 4;            // 0..15 -> channels cs and cs+16

        // hoist the 15 weight quads to registers (shared across both channels)
        float4a wv[SAMPLE_NUM];
        #pragma unroll
        for (int s = 0; s < SAMPLE_NUM; ++s)
            wv[s] = *(const float4a*)&w_lds[s][4 * q];

        #pragma unroll
        for (int half = 0; half < 2; ++half) {
            const int ch = half * 16 + cs;
            const float* fpl = &lds_f[ch * CH_STRIDE];

            float4a acc = {0.0f, 0.0f, 0.0f, 0.0f};
            #pragma unroll
            for (int s = 0; s < SAMPLE_NUM; ++s) {
                int pp = sample_idx[s];   // wave-uniform -> scalar
                int dy = pp / K_SIZE - PAD;
                int dx = pp - (pp / K_SIZE) * K_SIZE - PAD;
                int rr  = dy + 2;                    // staged row index
                int xi0 = 4 * q + dx + 2;            // staged col of quad start
                float4u f4 = *(const float4u*)&fpl[rr * WCOLS + xi0];
                acc += wv[s] * float4a{f4.x, f4.y, f4.z, f4.w};
            }

            const int gflat = planeBase + ch * HW + pix0 + 4 * q;
            float4a pf = *(const float4a*)(features + gflat);  // aligned passthrough
            *(float4a*)(out + gflat)      = acc;
            *(float4a*)(feat_out + gflat) = pf;
        }
    }
}

extern "C" void kernel_launch(void* const* d_in, const int* in_sizes, int n_in,
                              void* d_out, int out_size, void* d_ws, size_t ws_size,
                              hipStream_t stream) {
    const float* depth      = (const float*)d_in[0];
    const float* sn         = (const float*)d_in[1];
    const float* features   = (const float*)d_in[2];
    const float* guide      = (const float*)d_in[3];
    const int*   sample_idx = (const int*)d_in[4];

    float* out      = (float*)d_out;                      // [B,C,H,W]
    float* feat_out = (float*)d_out + (size_t)B * C * HW; // [B,C,H,W]

    adaptive_sample_fused<<<NBLK, 256, 0, stream>>>(
        depth, sn, features, guide, sample_idx, out, feat_out);
}

// Round 11
// 47.984 us; speedup vs baseline: 1.0025x; 1.0025x over previous
//
#include <hip/hip_runtime.h>

// Problem constants (match reference setup_inputs)
#define K_SIZE 5
#define PAD 2
#define SAMPLE_NUM 15
#define DEPTH_MAX 192.0f

constexpr int B = 2, C = 32, H = 240, W = 320;
constexpr int HW  = H * W;
constexpr int BHW = B * HW;            // 153600
constexpr int TOT = B * C * HW;        // 4915200 feature dwords
constexpr int PPB = 128;               // pixels per block
constexpr int NBLK = BHW / PPB;        // 1200
constexpr int XCHUNK = NBLK / 8;       // 150 contiguous blocks per XCD

typedef float float4a __attribute__((ext_vector_type(4), aligned(16)));
typedef float float4u __attribute__((ext_vector_type(4), aligned(4)));  // 4B-aligned ok

__global__ __launch_bounds__(256, 6) void adaptive_sample_fused(
    const float* __restrict__ depth,      // [B,1,H,W]
    const float* __restrict__ sn,         // [B,3,H,W]
    const float* __restrict__ features,   // [B,C,H,W]
    const float* __restrict__ guide,      // [B,H,W,25]
    const int*   __restrict__ sample_idx, // [15]
    float* __restrict__ out,              // [B,C,H,W]
    float* __restrict__ feat_out)         // [B,C,H,W]
{
    // weights only -- 7.7 KB LDS, no occupancy cap
    __shared__ __align__(16) float w_lds[SAMPLE_NUM][PPB];

    // XCD-chunked swizzle: each XCD owns 150 contiguous blocks
    const int bid = blockIdx.x;
    const int blk = (bid & 7) * XCHUNK + (bid >> 3);

    const int t    = threadIdx.x;
    const int base = blk * PPB;           // first global pixel
    const int b    = base / HW;           // uniform (128 | HW)
    const int pix0 = base - b * HW;

    const float* snb = sn + (size_t)b * 3 * HW;
    const float* db  = depth + (size_t)b * HW;

    // ---------------- phase 1: weights + 16-lane softmax -> w_lds ----------------
    {
        const int s  = t & 15;            // sample slot (15 = pad lane)
        const int lq = t >> 4;            // 0..15
        const int pp = sample_idx[(s < SAMPLE_NUM) ? s : 0];
        const int dy = pp / K_SIZE - PAD;
        const int dx = pp - (pp / K_SIZE) * K_SIZE - PAD;

        #pragma unroll
        for (int kk = 0; kk < 8; ++kk) {
            const int lp  = kk * 16 + lq;   // local pixel 0..127
            const int pix = pix0 + lp;
            const int y   = pix / W;
            const int x   = pix - y * W;

            const int yy = y + dy, xx = x + dx;
            const bool inb = (s < SAMPLE_NUM) &&
                             (yy >= 0) && (yy < H) && (xx >= 0) && (xx < W);
            const int noff = min(max(yy, 0), H - 1) * W + min(max(xx, 0), W - 1);

            // unconditional clamped loads; validity folded via selects
            const float d   = db[noff];
            const int   o   = pix * 3;  // center_n = RAW RESHAPE [B,3,H,W]->(B,H,W,3)
            const float cn0 = snb[o], cn1 = snb[o + 1], cn2 = snb[o + 2];
            const float d0  = snb[noff]          - cn0;
            const float d1  = snb[HW + noff]     - cn1;
            const float d2  = snb[2 * HW + noff] - cn2;
            const float gv  = guide[((size_t)b * HW + pix) * 25 + pp];

            const float diff = sqrtf(d0 * d0 + d1 * d1 + d2 * d2);
            const bool  ok   = inb && (d > 0.0f) && (d < DEPTH_MAX);
            const float prew = ok ? __expf(-0.5f * diff) * gv : 0.0f;

            // softmax across the 16-lane group (pad lane prew=0 can't raise max;
            // its exp term is excluded from the sum)
            float m = prew;
            #pragma unroll
            for (int mask = 1; mask < 16; mask <<= 1)
                m = fmaxf(m, __shfl_xor(m, mask, 16));
            float e = (s < SAMPLE_NUM) ? __expf(prew - m) : 0.0f;
            float sum = e;
            #pragma unroll
            for (int mask = 1; mask < 16; mask <<= 1)
                sum += __shfl_xor(sum, mask, 16);

            if (s < SAMPLE_NUM)
                w_lds[s][lp] = inb ? (e / sum) : 0.0f;  // OOB -> 0 (zero-pad feature)
        }
    }
    __syncthreads();

    // ---------------- phase 2: gather, thread = (quad, 4 channels) ----------------
    // Branch-free: weights are 0 at OOB -> unclamped flat reads (junk x 0 = 0);
    // only global buffer extremes clamp, with an exact fixup for the <=6 affected quads.
    {
        const int q    = t & 31;          // quad 0..31 (lanes = consecutive quads)
        const int grp  = t >> 5;          // 0..7 -> channels grp*4 .. grp*4+3
        const int ch0  = grp * 4;
        const int pixq = pix0 + 4 * q;    // within-batch first pixel of quad
        const int y    = pixq / W;
        const int x    = pixq - y * W;    // quads never cross rows (4 | W)
        const int pb0  = (b * C + ch0) * HW;   // global flat base of plane (b, ch0)

        float4a acc[4];
        #pragma unroll
        for (int cc = 0; cc < 4; ++cc) acc[cc] = float4a{0.f, 0.f, 0.f, 0.f};

        #pragma unroll
        for (int s = 0; s < SAMPLE_NUM; ++s) {
            int pp = sample_idx[s];       // wave-uniform -> scalar
            int dy = pp / K_SIZE - PAD;
            int dx = pp - (pp / K_SIZE) * K_SIZE - PAD;
            int yy = min(max(y + dy, 0), H - 1);   // OOB rows: w4 = 0
            int rb = yy * W + x + dx;              // UNCLAMPED x (w-masked)
            // lanes q=0..31 read consecutive b128 chunks; grp lanes broadcast -> conflict-free
            float4a w4 = *(const float4a*)&w_lds[s][4 * q];
            #pragma unroll
            for (int cc = 0; cc < 4; ++cc) {
                int flat = pb0 + cc * HW + rb;
                flat = min(max(flat, 0), TOT - 4); // only global extremes clamp
                float4u f4 = *(const float4u*)(features + flat);
                acc[cc] += w4 * float4a{f4.x, f4.y, f4.z, f4.w};
            }
        }

        // exact fixup wherever the flat clamp could have displaced a nonzero-weight read:
        // underflow: plane (0,0) reachable (y<=2) at x==0; overflow: plane (B-1,C-1) at x==W-4
        const bool fix = (pb0 == 0 && x == 0 && y <= 2) ||
                         (pb0 + 3 * HW == (B * C - 1) * HW && x == W - 4 && y >= H - 3);
        if (fix) {
            #pragma unroll
            for (int cc = 0; cc < 4; ++cc) {
                const float* fpl = features + pb0 + cc * HW;
                float a0 = 0, a1 = 0, a2 = 0, a3 = 0;
                for (int s = 0; s < SAMPLE_NUM; ++s) {
                    int pp = sample_idx[s];
                    int dy = pp / K_SIZE - PAD;
                    int dx = pp - (pp / K_SIZE) * K_SIZE - PAD;
                    int yy = min(max(y + dy, 0), H - 1);
                    const float* frow = fpl + yy * W;
                    int xb = x + dx;
                    a0 += w_lds[s][4 * q + 0] * frow[min(max(xb + 0, 0), W - 1)];
                    a1 += w_lds[s][4 * q + 1] * frow[min(max(xb + 1, 0), W - 1)];
                    a2 += w_lds[s][4 * q + 2] * frow[min(max(xb + 2, 0), W - 1)];
                    a3 += w_lds[s][4 * q + 3] * frow[min(max(xb + 3, 0), W - 1)];
                }
                acc[cc] = float4a{a0, a1, a2, a3};
            }
        }

        #pragma unroll
        for (int cc = 0; cc < 4; ++cc) {
            const int flat = pb0 + cc * HW + pixq;
            float4a pf = *(const float4a*)(features + flat);  // aligned passthrough
            *(float4a*)(out + flat)      = acc[cc];
            *(float4a*)(feat_out + flat) = pf;
        }
    }
}

extern "C" void kernel_launch(void* const* d_in, const int* in_sizes, int n_in,
                              void* d_out, int out_size, void* d_ws, size_t ws_size,
                              hipStream_t stream) {
    const float* depth      = (const float*)d_in[0];
    const float* sn         = (const float*)d_in[1];
    const float* features   = (const float*)d_in[2];
    const float* guide      = (const float*)d_in[3];
    const int*   sample_idx = (const int*)d_in[4];

    float* out      = (float*)d_out;                      // [B,C,H,W]
    float* feat_out = (float*)d_out + (size_t)B * C * HW; // [B,C,H,W]

    adaptive_sample_fused<<<NBLK, 256, 0, stream>>>(
        depth, sn, features, guide, sample_idx, out, feat_out);
}

// Round 12
// 43.395 us; speedup vs baseline: 1.1085x; 1.1057x over previous
//
#include <hip/hip_runtime.h>

// Problem constants (match reference setup_inputs)
#define K_SIZE 5
#define PAD 2
#define SAMPLE_NUM 15
#define DEPTH_MAX 192.0f

constexpr int B = 2, C = 32, H = 240, W = 320;
constexpr int HW  = H * W;
constexpr int BHW = B * HW;            // 153600
constexpr int TOT = B * C * HW;        // 4915200 feature dwords
constexpr int PPB = 64;                // pixels per block (16 quads)
constexpr int NBLK = BHW / PPB;        // 2400
constexpr int XCHUNK = NBLK / 8;       // 300 contiguous blocks per XCD

typedef float float4a __attribute__((ext_vector_type(4), aligned(16)));
typedef float float4u __attribute__((ext_vector_type(4), aligned(4)));  // 4B-aligned ok

__global__ __launch_bounds__(256, 4) void adaptive_sample_fused(
    const float* __restrict__ depth,      // [B,1,H,W]
    const float* __restrict__ sn,         // [B,3,H,W]
    const float* __restrict__ features,   // [B,C,H,W]
    const float* __restrict__ guide,      // [B,H,W,25]
    const int*   __restrict__ sample_idx, // [15]
    float* __restrict__ out,              // [B,C,H,W]
    float* __restrict__ feat_out)         // [B,C,H,W]
{
    // weights only -- 3.84 KB LDS
    __shared__ __align__(16) float w_lds[SAMPLE_NUM][PPB];

    // XCD-chunked swizzle: each XCD owns 300 contiguous blocks
    const int bid = blockIdx.x;
    const int blk = (bid & 7) * XCHUNK + (bid >> 3);

    const int t    = threadIdx.x;
    const int base = blk * PPB;           // first global pixel
    const int b    = base / HW;           // uniform (64 | HW)
    const int pix0 = base - b * HW;

    const float* snb = sn + (size_t)b * 3 * HW;
    const float* db  = depth + (size_t)b * HW;

    // ---------------- phase 1: weights + 16-lane softmax -> w_lds ----------------
    {
        const int s  = t & 15;            // sample slot (15 = pad lane)
        const int lq = t >> 4;            // 0..15
        const int pp = sample_idx[(s < SAMPLE_NUM) ? s : 0];
        const int dy = pp / K_SIZE - PAD;
        const int dx = pp - (pp / K_SIZE) * K_SIZE - PAD;

        #pragma unroll
        for (int kk = 0; kk < 4; ++kk) {
            const int lp  = kk * 16 + lq;   // local pixel 0..63
            const int pix = pix0 + lp;
            const int y   = pix / W;
            const int x   = pix - y * W;

            const int yy = y + dy, xx = x + dx;
            const bool inb = (s < SAMPLE_NUM) &&
                             (yy >= 0) && (yy < H) && (xx >= 0) && (xx < W);
            const int noff = min(max(yy, 0), H - 1) * W + min(max(xx, 0), W - 1);

            // unconditional clamped loads; validity folded via selects
            const float d   = db[noff];
            const int   o   = pix * 3;  // center_n = RAW RESHAPE [B,3,H,W]->(B,H,W,3)
            const float cn0 = snb[o], cn1 = snb[o + 1], cn2 = snb[o + 2];
            const float d0  = snb[noff]          - cn0;
            const float d1  = snb[HW + noff]     - cn1;
            const float d2  = snb[2 * HW + noff] - cn2;
            const float gv  = guide[((size_t)b * HW + pix) * 25 + pp];

            const float diff = sqrtf(d0 * d0 + d1 * d1 + d2 * d2);
            const bool  ok   = inb && (d > 0.0f) && (d < DEPTH_MAX);
            const float prew = ok ? __expf(-0.5f * diff) * gv : 0.0f;

            // softmax across the 16-lane group (pad lane prew=0 can't raise max;
            // its exp term is excluded from the sum)
            float m = prew;
            #pragma unroll
            for (int mask = 1; mask < 16; mask <<= 1)
                m = fmaxf(m, __shfl_xor(m, mask, 16));
            float e = (s < SAMPLE_NUM) ? __expf(prew - m) : 0.0f;
            float sum = e;
            #pragma unroll
            for (int mask = 1; mask < 16; mask <<= 1)
                sum += __shfl_xor(sum, mask, 16);

            if (s < SAMPLE_NUM)
                w_lds[s][lp] = inb ? (e / sum) : 0.0f;  // OOB -> 0 (zero-pad feature)
        }
    }
    __syncthreads();

    // ---------------- phase 2: gather, thread = (quad, 2 channels) ----------------
    // Branch-free loads: weights are 0 at OOB -> unclamped flat reads (junk x 0 = 0);
    // only global buffer extremes clamp, with an exact fixup for the few affected quads.
    // KEY: per channel, all 15 f4 loads are issued into a register array BEFORE any
    // FMA consumes them -> 15-deep VMEM clause per channel (ILP for latency hiding).
    {
        const int q    = t & 15;          // quad 0..15
        const int grp  = t >> 4;          // 0..15 -> channels 2*grp, 2*grp+1
        const int ch0  = grp * 2;
        const int pixq = pix0 + 4 * q;    // within-batch first pixel of quad
        const int y    = pixq / W;
        const int x    = pixq - y * W;    // quads never cross rows (4 | W)
        const int pb0  = (b * C + ch0) * HW;   // flat base of plane (b, ch0)

        // per-sample row-base offsets (shared by both channels)
        int rb[SAMPLE_NUM];
        #pragma unroll
        for (int s = 0; s < SAMPLE_NUM; ++s) {
            int pp = sample_idx[s];       // wave-uniform -> scalar
            int dy = pp / K_SIZE - PAD;
            int dx = pp - (pp / K_SIZE) * K_SIZE - PAD;
            int yy = min(max(y + dy, 0), H - 1);   // OOB rows: weights = 0
            rb[s] = yy * W + x + dx;               // UNCLAMPED x (w-masked)
        }

        float4a acc0 = {0.f, 0.f, 0.f, 0.f};
        float4a acc1 = {0.f, 0.f, 0.f, 0.f};
        {
            float4a fv[SAMPLE_NUM];       // channel ch0: 15-deep load clause
            #pragma unroll
            for (int s = 0; s < SAMPLE_NUM; ++s) {
                int flat = min(max(pb0 + rb[s], 0), TOT - 4);
                float4u f4 = *(const float4u*)(features + flat);
                fv[s] = float4a{f4.x, f4.y, f4.z, f4.w};
            }
            #pragma unroll
            for (int s = 0; s < SAMPLE_NUM; ++s)
                acc0 += *(const float4a*)&w_lds[s][4 * q] * fv[s];
        }
        {
            float4a fv[SAMPLE_NUM];       // channel ch0+1: 15-deep load clause
            #pragma unroll
            for (int s = 0; s < SAMPLE_NUM; ++s) {
                int flat = min(max(pb0 + HW + rb[s], 0), TOT - 4);
                float4u f4 = *(const float4u*)(features + flat);
                fv[s] = float4a{f4.x, f4.y, f4.z, f4.w};
            }
            #pragma unroll
            for (int s = 0; s < SAMPLE_NUM; ++s)
                acc1 += *(const float4a*)&w_lds[s][4 * q] * fv[s];
        }

        // exact fixup wherever the flat clamp could have displaced a nonzero-weight read:
        // underflow: plane (0,0) reachable (y<=2) at x==0; overflow: plane (B-1,C-1)
        const bool fix = (pb0 == 0 && x == 0 && y <= 2) ||
                         (pb0 + HW == (B * C - 1) * HW && x == W - 4 && y >= H - 3);
        if (fix) {
            #pragma unroll
            for (int cc = 0; cc < 2; ++cc) {
                const float* fpl = features + pb0 + cc * HW;
                float a0 = 0, a1 = 0, a2 = 0, a3 = 0;
                for (int s = 0; s < SAMPLE_NUM; ++s) {
                    int pp = sample_idx[s];
                    int dy = pp / K_SIZE - PAD;
                    int dx = pp - (pp / K_SIZE) * K_SIZE - PAD;
                    int yy = min(max(y + dy, 0), H - 1);
                    const float* frow = fpl + yy * W;
                    int xb = x + dx;
                    a0 += w_lds[s][4 * q + 0] * frow[min(max(xb + 0, 0), W - 1)];
                    a1 += w_lds[s][4 * q + 1] * frow[min(max(xb + 1, 0), W - 1)];
                    a2 += w_lds[s][4 * q + 2] * frow[min(max(xb + 2, 0), W - 1)];
                    a3 += w_lds[s][4 * q + 3] * frow[min(max(xb + 3, 0), W - 1)];
                }
                if (cc == 0) acc0 = float4a{a0, a1, a2, a3};
                else         acc1 = float4a{a0, a1, a2, a3};
            }
        }

        const int f0 = pb0 + pixq;
        const int f1 = pb0 + HW + pixq;
        float4a pf0 = *(const float4a*)(features + f0);   // aligned passthrough
        float4a pf1 = *(const float4a*)(features + f1);
        *(float4a*)(out + f0)      = acc0;
        *(float4a*)(out + f1)      = acc1;
        *(float4a*)(feat_out + f0) = pf0;
        *(float4a*)(feat_out + f1) = pf1;
    }
}

extern "C" void kernel_launch(void* const* d_in, const int* in_sizes, int n_in,
                              void* d_out, int out_size, void* d_ws, size_t ws_size,
                              hipStream_t stream) {
    const float* depth      = (const float*)d_in[0];
    const float* sn         = (const float*)d_in[1];
    const float* features   = (const float*)d_in[2];
    const float* guide      = (const float*)d_in[3];
    const int*   sample_idx = (const int*)d_in[4];

    float* out      = (float*)d_out;                      // [B,C,H,W]
    float* feat_out = (float*)d_out + (size_t)B * C * HW; // [B,C,H,W]

    adaptive_sample_fused<<<NBLK, 256, 0, stream>>>(
        depth, sn, features, guide, sample_idx, out, feat_out);
}